// Round 2
// baseline (1475.666 us; speedup 1.0000x reference)
//
#include <hip/hip_runtime.h>
#include <cstdint>

// ---------------- RNG scheme switch ----------------
// 0: partitionable stream, 32-bit draws = word0 ^ word1  (modern JAX default)
// 1: partitionable stream, word0 only
// 2: legacy split-iota stream
#define RNG_MODE 0

static constexpr int kUsers  = 100000;
static constexpr int kItems  = 200000;
static constexpr int kNodes  = 300000;   // kUsers + kItems
static constexpr int kEmb    = 64;
static constexpr int kHops   = 3;
static constexpr int kNnz    = 2000000;
static constexpr int kStride = kHops * kEmb;   // 192 floats per node row in d_out

#define MESS_SCALE ((float)(1.0 / 0.9))

// ---------------- threefry2x32, 20 rounds, JAX-compatible ----------------
__host__ __device__ inline void tf2x32(uint32_t k0, uint32_t k1, uint32_t& x0, uint32_t& x1) {
  uint32_t k2 = k0 ^ k1 ^ 0x1BD11BDAu;
  x0 += k0; x1 += k1;
#define TFR(r) { x0 += x1; x1 = (x1 << (r)) | (x1 >> (32 - (r))); x1 ^= x0; }
  TFR(13) TFR(15) TFR(26) TFR(6)
  x0 += k1; x1 += k2 + 1u;
  TFR(17) TFR(29) TFR(16) TFR(24)
  x0 += k2; x1 += k0 + 2u;
  TFR(13) TFR(15) TFR(26) TFR(6)
  x0 += k0; x1 += k1 + 3u;
  TFR(17) TFR(29) TFR(16) TFR(24)
  x0 += k1; x1 += k2 + 4u;
  TFR(13) TFR(15) TFR(26) TFR(6)
  x0 += k2; x1 += k0 + 5u;
#undef TFR
}

// one 32-bit draw for flat index i of an array with (even) size = 2*half
__device__ inline uint32_t draw_bits(uint32_t k0, uint32_t k1, uint32_t i, uint32_t half) {
#if RNG_MODE == 0
  uint32_t x0 = 0u, x1 = i;          // counter: hi=0 (size < 2^32), lo=i
  tf2x32(k0, k1, x0, x1);
  return x0 ^ x1;                    // _threefry_random_bits_partitionable, bit_width 32
#elif RNG_MODE == 1
  uint32_t x0 = 0u, x1 = i;
  tf2x32(k0, k1, x0, x1);
  return x0;
#else
  uint32_t lo = (i < half) ? i : (i - half);
  uint32_t x0 = lo, x1 = lo + half;  // legacy: iota split into two halves
  tf2x32(k0, k1, x0, x1);
  return (i < half) ? x0 : x1;
#endif
}

__device__ inline float bits_to_unit(uint32_t bits) {
  return __uint_as_float((bits >> 9) | 0x3F800000u) - 1.0f;  // [0,1), JAX _uniform
}

// ---------------- kernels ----------------

// per-edge dropped+rescaled adjacency value for this hop
__global__ void edge_vals_k(const float* __restrict__ adj_vals, float* __restrict__ v_out,
                            uint32_t ek0, uint32_t ek1) {
  int e = blockIdx.x * blockDim.x + threadIdx.x;
  if (e >= kNnz) return;
  uint32_t bits = draw_bits(ek0, ek1, (uint32_t)e, (uint32_t)(kNnz / 2));
  // keep iff floor(0.5 + u) > 0  <=>  u >= 0.5  <=>  top bit set (exact: u is k*2^-23)
  float v = (bits & 0x80000000u) ? adj_vals[e] * 2.0f : 0.0f;
  v_out[e] = v;
}

// scatter SpMM: one lane per (edge, dim). acc points at d_out + hop*kEmb (stride kStride).
// prev == nullptr for hop 0 (read the two embedding inputs directly).
__global__ void scatter_k(const int* __restrict__ rows, const int* __restrict__ cols,
                          const float* __restrict__ vvals,
                          const float* __restrict__ user_emb, const float* __restrict__ item_emb,
                          const float* __restrict__ prev,
                          float* __restrict__ acc) {
  long long t = (long long)blockIdx.x * blockDim.x + threadIdx.x;
  int e = (int)(t >> 6);
  int d = (int)(t & 63);
  if (e >= kNnz) return;
  float ve = vvals[e];
  if (ve == 0.0f) return;          // dropped edge: whole wave exits
  int c = cols[e];
  int r = rows[e];
  float x;
  if (prev) {
    x = prev[(long long)c * kStride + d];
  } else {
    x = (c < kUsers) ? user_emb[(long long)c * kEmb + d]
                     : item_emb[(long long)(c - kUsers) * kEmb + d];
  }
  unsafeAtomicAdd(&acc[(long long)r * kStride + d], ve * x);
}

// in-place message dropout on this hop's slice of d_out
__global__ void mess_k(float* __restrict__ slice, uint32_t mk0, uint32_t mk1) {
  long long i = (long long)blockIdx.x * blockDim.x + threadIdx.x;
  const long long total = (long long)kNodes * kEmb;
  if (i >= total) return;
  uint32_t bits = draw_bits(mk0, mk1, (uint32_t)i, (uint32_t)(total / 2));
  float u = bits_to_unit(bits);
  int n = (int)(i >> 6), d = (int)(i & 63);
  long long idx = (long long)n * kStride + d;
  float val = slice[idx];
  slice[idx] = (u >= 0.1f) ? val * MESS_SCALE : 0.0f;
}

// ---------------- launch ----------------
extern "C" void kernel_launch(void* const* d_in, const int* in_sizes, int n_in,
                              void* d_out, int out_size, void* d_ws, size_t ws_size,
                              hipStream_t stream) {
  const float* user_emb = (const float*)d_in[0];
  const float* item_emb = (const float*)d_in[1];
  const float* adj_vals = (const float*)d_in[2];
  const int*   adj_rows = (const int*)d_in[3];
  const int*   adj_cols = (const int*)d_in[4];
  float* out  = (float*)d_out;
  float* vbuf = (float*)d_ws;       // kNnz floats = 8 MB scratch

  // zero the whole output once; each hop accumulates into its strided slice
  hipMemsetAsync(d_out, 0, (size_t)out_size * sizeof(float), stream);

  for (int hop = 0; hop < kHops; ++hop) {
    // host-side key derivation: fold_in(key(42), d) = threefry block of (0, d) under (0, 42)
    uint32_t ek0 = 0u, ek1 = (uint32_t)(2 * hop);
    tf2x32(0u, 42u, ek0, ek1);
    uint32_t mk0 = 0u, mk1 = (uint32_t)(2 * hop + 1);
    tf2x32(0u, 42u, mk0, mk1);

    edge_vals_k<<<(kNnz + 255) / 256, 256, 0, stream>>>(adj_vals, vbuf, ek0, ek1);

    const float* prev = (hop == 0) ? nullptr : (out + (long long)(hop - 1) * kEmb);
    float* acc = out + (long long)hop * kEmb;
    long long nthreads = (long long)kNnz * 64;
    scatter_k<<<(int)((nthreads + 255) / 256), 256, 0, stream>>>(
        adj_rows, adj_cols, vbuf, user_emb, item_emb, prev, acc);

    long long etotal = (long long)kNodes * kEmb;
    mess_k<<<(int)((etotal + 255) / 256), 256, 0, stream>>>(acc, mk0, mk1);
  }
}

// Round 3
// 1172.228 us; speedup vs baseline: 1.2589x; 1.2589x over previous
//
#include <hip/hip_runtime.h>
#include <cstdint>

static constexpr int kUsers  = 100000;
static constexpr int kItems  = 200000;
static constexpr int kNodes  = 300000;   // kUsers + kItems
static constexpr int kEmb    = 64;
static constexpr int kHops   = 3;
static constexpr int kNnz    = 2000000;
static constexpr int kStride = kHops * kEmb;   // 192 floats per node row in d_out

#define MESS_SCALE ((float)(1.0 / 0.9))

// ---------------- threefry2x32, 20 rounds, JAX-compatible ----------------
__host__ __device__ inline void tf2x32(uint32_t k0, uint32_t k1, uint32_t& x0, uint32_t& x1) {
  uint32_t k2 = k0 ^ k1 ^ 0x1BD11BDAu;
  x0 += k0; x1 += k1;
#define TFR(r) { x0 += x1; x1 = (x1 << (r)) | (x1 >> (32 - (r))); x1 ^= x0; }
  TFR(13) TFR(15) TFR(26) TFR(6)
  x0 += k1; x1 += k2 + 1u;
  TFR(17) TFR(29) TFR(16) TFR(24)
  x0 += k2; x1 += k0 + 2u;
  TFR(13) TFR(15) TFR(26) TFR(6)
  x0 += k0; x1 += k1 + 3u;
  TFR(17) TFR(29) TFR(16) TFR(24)
  x0 += k1; x1 += k2 + 4u;
  TFR(13) TFR(15) TFR(26) TFR(6)
  x0 += k2; x1 += k0 + 5u;
#undef TFR
}

// JAX partitionable stream, 32-bit draws: threefry(key, hi=0, lo=i), word0 ^ word1
__device__ inline uint32_t draw_bits(uint32_t k0, uint32_t k1, uint32_t i) {
  uint32_t x0 = 0u, x1 = i;
  tf2x32(k0, k1, x0, x1);
  return x0 ^ x1;
}

__device__ inline float bits_to_unit(uint32_t bits) {
  return __uint_as_float((bits >> 9) | 0x3F800000u) - 1.0f;  // [0,1), JAX _uniform
}

// ================= CSR build (once per launch; graph is hop-invariant) =================

__global__ void hist_k(const int* __restrict__ rows, int* __restrict__ deg) {
  int e = blockIdx.x * blockDim.x + threadIdx.x;
  if (e < kNnz) atomicAdd(&deg[rows[e]], 1);
}

// wave-level exclusive scan + one global atomic per wave -> contiguous segment per row.
// Segment ordering across rows is arbitrary (fp32 sum order already differs from ref).
__global__ void alloc_k(const int* __restrict__ deg, int* __restrict__ start,
                        int* __restrict__ cur, int* __restrict__ cursor) {
  int r = blockIdx.x * blockDim.x + threadIdx.x;
  int lane = threadIdx.x & 63;
  int d = (r < kNodes) ? deg[r] : 0;
  int x = d;
  for (int off = 1; off < 64; off <<= 1) {
    int y = __shfl_up(x, off);
    if (lane >= off) x += y;
  }
  int excl = x - d;
  int total = __shfl(x, 63);
  int base = 0;
  if (lane == 63) base = atomicAdd(cursor, total);
  base = __shfl(base, 63);
  if (r < kNodes) { start[r] = base + excl; cur[r] = base + excl; }
}

__global__ void fill_k(const int* __restrict__ rows, const int* __restrict__ cols,
                       const float* __restrict__ vals, int* __restrict__ cur,
                       int* __restrict__ cols_s, float* __restrict__ vals_s,
                       int* __restrict__ eid_s) {
  int e = blockIdx.x * blockDim.x + threadIdx.x;
  if (e >= kNnz) return;
  int r = rows[e];
  int p = atomicAdd(&cur[r], 1);
  cols_s[p] = cols[e];
  vals_s[p] = vals[e];
  eid_s[p]  = e;
}

// ================= per-hop kernels =================

// dropped+rescaled adjacency values in CSR order; RNG keyed by ORIGINAL edge id
__global__ void edge_vals_csr_k(const int* __restrict__ eid_s, const float* __restrict__ vals_s,
                                float* __restrict__ vbuf, uint32_t ek0, uint32_t ek1) {
  int p = blockIdx.x * blockDim.x + threadIdx.x;
  if (p >= kNnz) return;
  uint32_t bits = draw_bits(ek0, ek1, (uint32_t)eid_s[p]);
  // keep iff floor(0.5+u) > 0 <=> u >= 0.5 <=> top bit set (exact: u = k*2^-23)
  vbuf[p] = (bits & 0x80000000u) ? vals_s[p] * 2.0f : 0.0f;
}

// one wave per row, lane = emb dim. Gathers prev rows (coalesced 256B), accumulates in
// a register, applies message dropout inline, writes this hop's slice of d_out once.
__global__ void row_gather_k(const int* __restrict__ start, const int* __restrict__ deg,
                             const int* __restrict__ cols_s, const float* __restrict__ vbuf,
                             const float* __restrict__ user_emb, const float* __restrict__ item_emb,
                             const float* __restrict__ prev,   // nullptr for hop 0
                             float* __restrict__ out, uint32_t mk0, uint32_t mk1, int hop) {
  int wid = (int)(((long long)blockIdx.x * blockDim.x + threadIdx.x) >> 6);  // row
  int d = threadIdx.x & 63;
  if (wid >= kNodes) return;
  int s = start[wid];
  int n = deg[wid];
  float acc = 0.0f;
  // 1-deep software pipeline on the (wave-uniform, broadcast) index loads
  float v = 0.0f; int c = 0;
  if (n > 0) { v = vbuf[s]; c = cols_s[s]; }
  for (int k = 0; k < n; ++k) {
    float vn = 0.0f; int cn = 0;
    if (k + 1 < n) { vn = vbuf[s + k + 1]; cn = cols_s[s + k + 1]; }
    if (v != 0.0f) {
      float x;
      if (prev) {
        x = prev[(long long)c * kStride + d];
      } else {
        x = (c < kUsers) ? user_emb[(long long)c * kEmb + d]
                         : item_emb[(long long)(c - kUsers) * kEmb + d];
      }
      acc += v * x;
    }
    v = vn; c = cn;
  }
  // message dropout on agg[wid, d]: flat index over (kNodes, kEmb)
  uint32_t bits = draw_bits(mk0, mk1, (uint32_t)(wid * kEmb + d));
  float u = bits_to_unit(bits);
  float res = (u >= 0.1f) ? acc * MESS_SCALE : 0.0f;
  out[(long long)wid * kStride + hop * kEmb + d] = res;
}

// ================= fallback path (round-2 proven; used if ws too small) =================

__global__ void edge_vals_k(const float* __restrict__ adj_vals, float* __restrict__ v_out,
                            uint32_t ek0, uint32_t ek1) {
  int e = blockIdx.x * blockDim.x + threadIdx.x;
  if (e >= kNnz) return;
  uint32_t bits = draw_bits(ek0, ek1, (uint32_t)e);
  v_out[e] = (bits & 0x80000000u) ? adj_vals[e] * 2.0f : 0.0f;
}

__global__ void scatter_k(const int* __restrict__ rows, const int* __restrict__ cols,
                          const float* __restrict__ vvals,
                          const float* __restrict__ user_emb, const float* __restrict__ item_emb,
                          const float* __restrict__ prev, float* __restrict__ acc) {
  long long t = (long long)blockIdx.x * blockDim.x + threadIdx.x;
  int e = (int)(t >> 6);
  int d = (int)(t & 63);
  if (e >= kNnz) return;
  float ve = vvals[e];
  if (ve == 0.0f) return;
  int c = cols[e];
  int r = rows[e];
  float x;
  if (prev) x = prev[(long long)c * kStride + d];
  else x = (c < kUsers) ? user_emb[(long long)c * kEmb + d]
                        : item_emb[(long long)(c - kUsers) * kEmb + d];
  unsafeAtomicAdd(&acc[(long long)r * kStride + d], ve * x);
}

__global__ void mess_k(float* __restrict__ slice, uint32_t mk0, uint32_t mk1) {
  long long i = (long long)blockIdx.x * blockDim.x + threadIdx.x;
  const long long total = (long long)kNodes * kEmb;
  if (i >= total) return;
  uint32_t bits = draw_bits(mk0, mk1, (uint32_t)i);
  float u = bits_to_unit(bits);
  int n = (int)(i >> 6), d = (int)(i & 63);
  long long idx = (long long)n * kStride + d;
  float val = slice[idx];
  slice[idx] = (u >= 0.1f) ? val * MESS_SCALE : 0.0f;
}

// ================= launch =================

extern "C" void kernel_launch(void* const* d_in, const int* in_sizes, int n_in,
                              void* d_out, int out_size, void* d_ws, size_t ws_size,
                              hipStream_t stream) {
  const float* user_emb = (const float*)d_in[0];
  const float* item_emb = (const float*)d_in[1];
  const float* adj_vals = (const float*)d_in[2];
  const int*   adj_rows = (const int*)d_in[3];
  const int*   adj_cols = (const int*)d_in[4];
  float* out = (float*)d_out;

  // ws layout (bytes, 512-aligned)
  char* base = (char*)d_ws;
  const size_t off_deg    = 0;                         // kNodes int
  const size_t off_start  = 1200128;                   // kNodes int
  const size_t off_cur    = 2400256;                   // kNodes int
  const size_t off_cursor = 3600384;                   // 1 int
  const size_t off_cols   = 3600896;                   // kNnz int
  const size_t off_vals   = 11600896;                  // kNnz float
  const size_t off_eid    = 19600896;                  // kNnz int
  const size_t off_vbuf   = 27600896;                  // kNnz float
  const size_t needed     = 35600896;

  uint32_t ek0[kHops], ek1[kHops], mk0[kHops], mk1[kHops];
  for (int hop = 0; hop < kHops; ++hop) {
    ek0[hop] = 0u; ek1[hop] = (uint32_t)(2 * hop);
    tf2x32(0u, 42u, ek0[hop], ek1[hop]);   // fold_in(key(42), 2h)
    mk0[hop] = 0u; mk1[hop] = (uint32_t)(2 * hop + 1);
    tf2x32(0u, 42u, mk0[hop], mk1[hop]);   // fold_in(key(42), 2h+1)
  }

  if (ws_size >= needed) {
    int*   deg    = (int*)(base + off_deg);
    int*   start  = (int*)(base + off_start);
    int*   cur    = (int*)(base + off_cur);
    int*   cursor = (int*)(base + off_cursor);
    int*   cols_s = (int*)(base + off_cols);
    float* vals_s = (float*)(base + off_vals);
    int*   eid_s  = (int*)(base + off_eid);
    float* vbuf   = (float*)(base + off_vbuf);

    hipMemsetAsync(deg, 0, (size_t)kNodes * sizeof(int), stream);
    hipMemsetAsync(cursor, 0, sizeof(int), stream);

    hist_k<<<(kNnz + 255) / 256, 256, 0, stream>>>(adj_rows, deg);
    alloc_k<<<(kNodes + 255) / 256, 256, 0, stream>>>(deg, start, cur, cursor);
    fill_k<<<(kNnz + 255) / 256, 256, 0, stream>>>(adj_rows, adj_cols, adj_vals,
                                                   cur, cols_s, vals_s, eid_s);

    for (int hop = 0; hop < kHops; ++hop) {
      edge_vals_csr_k<<<(kNnz + 255) / 256, 256, 0, stream>>>(eid_s, vals_s, vbuf,
                                                              ek0[hop], ek1[hop]);
      const float* prev = (hop == 0) ? nullptr : (out + (long long)(hop - 1) * kEmb);
      long long nthreads = (long long)kNodes * 64;
      row_gather_k<<<(int)((nthreads + 255) / 256), 256, 0, stream>>>(
          start, deg, cols_s, vbuf, user_emb, item_emb, prev, out,
          mk0[hop], mk1[hop], hop);
    }
  } else {
    // fallback: round-2 scatter path (needs only kNnz floats of ws)
    float* vbuf = (float*)d_ws;
    hipMemsetAsync(d_out, 0, (size_t)out_size * sizeof(float), stream);
    for (int hop = 0; hop < kHops; ++hop) {
      edge_vals_k<<<(kNnz + 255) / 256, 256, 0, stream>>>(adj_vals, vbuf, ek0[hop], ek1[hop]);
      const float* prev = (hop == 0) ? nullptr : (out + (long long)(hop - 1) * kEmb);
      float* acc = out + (long long)hop * kEmb;
      long long nthreads = (long long)kNnz * 64;
      scatter_k<<<(int)((nthreads + 255) / 256), 256, 0, stream>>>(
          adj_rows, adj_cols, vbuf, user_emb, item_emb, prev, acc);
      long long etotal = (long long)kNodes * kEmb;
      mess_k<<<(int)((etotal + 255) / 256), 256, 0, stream>>>(acc, mk0[hop], mk1[hop]);
    }
  }
}

// Round 4
// 974.230 us; speedup vs baseline: 1.5147x; 1.2032x over previous
//
#include <hip/hip_runtime.h>
#include <cstdint>

static constexpr int kUsers  = 100000;
static constexpr int kItems  = 200000;
static constexpr int kNodes  = 300000;   // kUsers + kItems
static constexpr int kEmb    = 64;
static constexpr int kHops   = 3;
static constexpr int kNnz    = 2000000;
static constexpr int kStride = kHops * kEmb;   // 192 floats per node row in d_out

#define MESS_SCALE ((float)(1.0 / 0.9))

// ---------------- threefry2x32, 20 rounds, JAX-compatible ----------------
__host__ __device__ inline void tf2x32(uint32_t k0, uint32_t k1, uint32_t& x0, uint32_t& x1) {
  uint32_t k2 = k0 ^ k1 ^ 0x1BD11BDAu;
  x0 += k0; x1 += k1;
#define TFR(r) { x0 += x1; x1 = (x1 << (r)) | (x1 >> (32 - (r))); x1 ^= x0; }
  TFR(13) TFR(15) TFR(26) TFR(6)
  x0 += k1; x1 += k2 + 1u;
  TFR(17) TFR(29) TFR(16) TFR(24)
  x0 += k2; x1 += k0 + 2u;
  TFR(13) TFR(15) TFR(26) TFR(6)
  x0 += k0; x1 += k1 + 3u;
  TFR(17) TFR(29) TFR(16) TFR(24)
  x0 += k1; x1 += k2 + 4u;
  TFR(13) TFR(15) TFR(26) TFR(6)
  x0 += k2; x1 += k0 + 5u;
#undef TFR
}

// JAX partitionable stream, 32-bit draws: threefry(key, hi=0, lo=i), word0 ^ word1
__device__ inline uint32_t draw_bits(uint32_t k0, uint32_t k1, uint32_t i) {
  uint32_t x0 = 0u, x1 = i;
  tf2x32(k0, k1, x0, x1);
  return x0 ^ x1;
}

__device__ inline float bits_to_unit(uint32_t bits) {
  return __uint_as_float((bits >> 9) | 0x3F800000u) - 1.0f;  // [0,1), JAX _uniform
}

// ================= CSR build (once per launch; graph is hop-invariant) =================
// Edge record: int4 {x=col, y=eid, z=val(bits), w=per-hop dropped value (bits)}

__global__ void hist_k(const int* __restrict__ rows, int* __restrict__ deg) {
  int e = blockIdx.x * blockDim.x + threadIdx.x;
  if (e < kNnz) atomicAdd(&deg[rows[e]], 1);
}

// wave-level exclusive scan + one global atomic per wave -> contiguous segment per row.
// Segment ordering across rows is arbitrary (fp32 sum order already differs from ref).
__global__ void alloc_k(const int* __restrict__ deg, int* __restrict__ start,
                        int* __restrict__ cur, int* __restrict__ cursor) {
  int r = blockIdx.x * blockDim.x + threadIdx.x;
  int lane = threadIdx.x & 63;
  int d = (r < kNodes) ? deg[r] : 0;
  int x = d;
  for (int off = 1; off < 64; off <<= 1) {
    int y = __shfl_up(x, off);
    if (lane >= off) x += y;
  }
  int excl = x - d;
  int total = __shfl(x, 63);
  int base = 0;
  if (lane == 63) base = atomicAdd(cursor, total);
  base = __shfl(base, 63);
  if (r < kNodes) { start[r] = base + excl; cur[r] = base + excl; }
}

// after fill completes, cur[r] == start[r] + deg[r] == row end pointer
__global__ void fill_k(const int* __restrict__ rows, const int* __restrict__ cols,
                       const float* __restrict__ vals, int* __restrict__ cur,
                       int4* __restrict__ pv) {
  int e = blockIdx.x * blockDim.x + threadIdx.x;
  if (e >= kNnz) return;
  int r = rows[e];
  int p = atomicAdd(&cur[r], 1);
  pv[p] = make_int4(cols[e], e, __float_as_int(vals[e]), 0);
}

// ================= per-hop kernels =================

// write this hop's dropped+rescaled value into pv[p].w; RNG keyed by ORIGINAL edge id
__global__ void edge_vals_csr_k(int4* __restrict__ pv, uint32_t ek0, uint32_t ek1) {
  int p = blockIdx.x * blockDim.x + threadIdx.x;
  if (p >= kNnz) return;
  int4 ee = pv[p];
  uint32_t bits = draw_bits(ek0, ek1, (uint32_t)ee.y);
  // keep iff floor(0.5+u) > 0 <=> u >= 0.5 <=> top bit set (exact: u = k*2^-23)
  float v = (bits & 0x80000000u) ? __int_as_float(ee.z) * 2.0f : 0.0f;
  ((int*)pv)[4 * p + 3] = __float_as_int(v);
}

// one wave per row, lane = emb dim. 4-wide unrolled gather loop (end-clamped, v=0 on
// duplicates), unconditional gathers -> 4 loads in flight. Fused message dropout + store.
template <bool HOP0>
__global__ void row_gather_k(const int* __restrict__ start, const int* __restrict__ endp,
                             const int4* __restrict__ pv,
                             const float* __restrict__ ue, const float* __restrict__ ie,
                             const float* __restrict__ prev,   // hop>=1 source slice
                             float* __restrict__ out, uint32_t mk0, uint32_t mk1, int hop) {
  int wid = (int)(((long long)blockIdx.x * blockDim.x + threadIdx.x) >> 6);  // row
  int d = threadIdx.x & 63;
  if (wid >= kNodes) return;
  int s = endp ? start[wid] : 0;   // (endp always non-null; keeps compiler honest)
  int e = endp[wid];
  float acc = 0.0f;
  const float* isft = ie - (long long)kUsers * kEmb;  // item base shifted by user count
  for (int k = s; k < e; k += 4) {
    int i1 = (k + 1 < e) ? k + 1 : e - 1;
    int i2 = (k + 2 < e) ? k + 2 : e - 1;
    int i3 = (k + 3 < e) ? k + 3 : e - 1;
    int4 e0 = pv[k], e1 = pv[i1], e2 = pv[i2], e3 = pv[i3];
    float v0 = __int_as_float(e0.w);
    float v1 = (k + 1 < e) ? __int_as_float(e1.w) : 0.0f;
    float v2 = (k + 2 < e) ? __int_as_float(e2.w) : 0.0f;
    float v3 = (k + 3 < e) ? __int_as_float(e3.w) : 0.0f;
    float x0, x1, x2, x3;
    if (HOP0) {
      const float* b0 = (e0.x < kUsers) ? ue : isft;
      const float* b1 = (e1.x < kUsers) ? ue : isft;
      const float* b2 = (e2.x < kUsers) ? ue : isft;
      const float* b3 = (e3.x < kUsers) ? ue : isft;
      x0 = b0[(long long)e0.x * kEmb + d];
      x1 = b1[(long long)e1.x * kEmb + d];
      x2 = b2[(long long)e2.x * kEmb + d];
      x3 = b3[(long long)e3.x * kEmb + d];
    } else {
      x0 = prev[(long long)e0.x * kStride + d];
      x1 = prev[(long long)e1.x * kStride + d];
      x2 = prev[(long long)e2.x * kStride + d];
      x3 = prev[(long long)e3.x * kStride + d];
    }
    acc += v0 * x0 + v1 * x1 + v2 * x2 + v3 * x3;
  }
  // message dropout on agg[wid, d]: flat index over (kNodes, kEmb)
  uint32_t bits = draw_bits(mk0, mk1, (uint32_t)(wid * kEmb + d));
  float u = bits_to_unit(bits);
  float res = (u >= 0.1f) ? acc * MESS_SCALE : 0.0f;
  out[(long long)wid * kStride + hop * kEmb + d] = res;
}

// ================= fallback path (round-2 proven; used if ws too small) =================

__global__ void edge_vals_k(const float* __restrict__ adj_vals, float* __restrict__ v_out,
                            uint32_t ek0, uint32_t ek1) {
  int e = blockIdx.x * blockDim.x + threadIdx.x;
  if (e >= kNnz) return;
  uint32_t bits = draw_bits(ek0, ek1, (uint32_t)e);
  v_out[e] = (bits & 0x80000000u) ? adj_vals[e] * 2.0f : 0.0f;
}

__global__ void scatter_k(const int* __restrict__ rows, const int* __restrict__ cols,
                          const float* __restrict__ vvals,
                          const float* __restrict__ user_emb, const float* __restrict__ item_emb,
                          const float* __restrict__ prev, float* __restrict__ acc) {
  long long t = (long long)blockIdx.x * blockDim.x + threadIdx.x;
  int e = (int)(t >> 6);
  int d = (int)(t & 63);
  if (e >= kNnz) return;
  float ve = vvals[e];
  if (ve == 0.0f) return;
  int c = cols[e];
  int r = rows[e];
  float x;
  if (prev) x = prev[(long long)c * kStride + d];
  else x = (c < kUsers) ? user_emb[(long long)c * kEmb + d]
                        : item_emb[(long long)(c - kUsers) * kEmb + d];
  unsafeAtomicAdd(&acc[(long long)r * kStride + d], ve * x);
}

__global__ void mess_k(float* __restrict__ slice, uint32_t mk0, uint32_t mk1) {
  long long i = (long long)blockIdx.x * blockDim.x + threadIdx.x;
  const long long total = (long long)kNodes * kEmb;
  if (i >= total) return;
  uint32_t bits = draw_bits(mk0, mk1, (uint32_t)i);
  float u = bits_to_unit(bits);
  int n = (int)(i >> 6), d = (int)(i & 63);
  long long idx = (long long)n * kStride + d;
  float val = slice[idx];
  slice[idx] = (u >= 0.1f) ? val * MESS_SCALE : 0.0f;
}

// ================= launch =================

extern "C" void kernel_launch(void* const* d_in, const int* in_sizes, int n_in,
                              void* d_out, int out_size, void* d_ws, size_t ws_size,
                              hipStream_t stream) {
  const float* user_emb = (const float*)d_in[0];
  const float* item_emb = (const float*)d_in[1];
  const float* adj_vals = (const float*)d_in[2];
  const int*   adj_rows = (const int*)d_in[3];
  const int*   adj_cols = (const int*)d_in[4];
  float* out = (float*)d_out;

  // ws layout (bytes; pv offset 16B-aligned)
  char* base = (char*)d_ws;
  const size_t off_deg    = 0;          // kNodes int
  const size_t off_start  = 1200128;    // kNodes int
  const size_t off_cur    = 2400256;    // kNodes int (becomes row-end after fill)
  const size_t off_cursor = 3600384;    // 1 int
  const size_t off_pv     = 3600896;    // kNnz int4 (32,000,000 B)
  const size_t needed     = 35600896;   // == round-3 proven footprint

  uint32_t ek0[kHops], ek1[kHops], mk0[kHops], mk1[kHops];
  for (int hop = 0; hop < kHops; ++hop) {
    ek0[hop] = 0u; ek1[hop] = (uint32_t)(2 * hop);
    tf2x32(0u, 42u, ek0[hop], ek1[hop]);   // fold_in(key(42), 2h)
    mk0[hop] = 0u; mk1[hop] = (uint32_t)(2 * hop + 1);
    tf2x32(0u, 42u, mk0[hop], mk1[hop]);   // fold_in(key(42), 2h+1)
  }

  if (ws_size >= needed) {
    int*  deg    = (int*)(base + off_deg);
    int*  start  = (int*)(base + off_start);
    int*  cur    = (int*)(base + off_cur);
    int*  cursor = (int*)(base + off_cursor);
    int4* pv     = (int4*)(base + off_pv);

    hipMemsetAsync(deg, 0, (size_t)kNodes * sizeof(int), stream);
    hipMemsetAsync(cursor, 0, sizeof(int), stream);

    hist_k<<<(kNnz + 255) / 256, 256, 0, stream>>>(adj_rows, deg);
    alloc_k<<<(kNodes + 255) / 256, 256, 0, stream>>>(deg, start, cur, cursor);
    fill_k<<<(kNnz + 255) / 256, 256, 0, stream>>>(adj_rows, adj_cols, adj_vals, cur, pv);

    long long nthreads = (long long)kNodes * 64;
    int ngrid = (int)((nthreads + 255) / 256);
    for (int hop = 0; hop < kHops; ++hop) {
      edge_vals_csr_k<<<(kNnz + 255) / 256, 256, 0, stream>>>(pv, ek0[hop], ek1[hop]);
      if (hop == 0) {
        row_gather_k<true><<<ngrid, 256, 0, stream>>>(
            start, cur, pv, user_emb, item_emb, nullptr, out, mk0[hop], mk1[hop], hop);
      } else {
        const float* prev = out + (long long)(hop - 1) * kEmb;
        row_gather_k<false><<<ngrid, 256, 0, stream>>>(
            start, cur, pv, user_emb, item_emb, prev, out, mk0[hop], mk1[hop], hop);
      }
    }
  } else {
    // fallback: round-2 scatter path (needs only kNnz floats of ws)
    float* vbuf = (float*)d_ws;
    hipMemsetAsync(d_out, 0, (size_t)out_size * sizeof(float), stream);
    for (int hop = 0; hop < kHops; ++hop) {
      edge_vals_k<<<(kNnz + 255) / 256, 256, 0, stream>>>(adj_vals, vbuf, ek0[hop], ek1[hop]);
      const float* prev = (hop == 0) ? nullptr : (out + (long long)(hop - 1) * kEmb);
      float* acc = out + (long long)hop * kEmb;
      long long nthreads = (long long)kNnz * 64;
      scatter_k<<<(int)((nthreads + 255) / 256), 256, 0, stream>>>(
          adj_rows, adj_cols, vbuf, user_emb, item_emb, prev, acc);
      long long etotal = (long long)kNodes * kEmb;
      mess_k<<<(int)((etotal + 255) / 256), 256, 0, stream>>>(acc, mk0[hop], mk1[hop]);
    }
  }
}